// Round 1
// baseline (577.668 us; speedup 1.0000x reference)
//
#include <hip/hip_runtime.h>

#define VOCAB   50000
#define LDIM    8921
#define DDIM    300
#define DPAD    320
#define KSZ     10
#define BATCH   8
#define TSEQ    2048
#define PADL    9
#define TPRIME  2057
#define TPADDED 2066
#define LPAD    8928

// ---- attn tiling
#define TSTG    32                 // t rows per LDS tile
#define NTT     65                 // ceil(TPRIME/TSTG)
#define TALLOC  (NTT * TSTG)       // 2080 h rows allocated per batch (tail rows masked)
#define HSTR    328                // LDS row stride (elems): 656B -> 2-way conflict max (free)
#define LBLK    70                 // ceil(LDIM/128) l-blocks

typedef short s8v __attribute__((ext_vector_type(8)));   // 8 x bf16 bits
typedef float f4v __attribute__((ext_vector_type(4)));

__device__ inline unsigned short f2bf(float f) {
  union { float f; unsigned u; } v; v.f = f;
  unsigned r = v.u + 0x7FFF + ((v.u >> 16) & 1);
  return (unsigned short)(r >> 16);
}

// ---- K1: embedding gather -> xp_bf16[b][tau][DPAD], zero-padded rows/cols
__global__ __launch_bounds__(256) void gather_kernel(
    const int* __restrict__ ids, const float* __restrict__ embed_w,
    unsigned short* __restrict__ xp) {
  int wid = blockIdx.x * 4 + (threadIdx.x >> 6);
  int lane = threadIdx.x & 63;
  int b = wid / TPADDED, tau = wid % TPADDED;
  bool inr = (tau >= PADL) && (tau < PADL + TSEQ);
  int row = inr ? ids[b * TSEQ + (tau - PADL)] : 0;
  const float* src = embed_w + (size_t)row * DDIM;
  unsigned short* dst = xp + ((size_t)b * TPADDED + tau) * DPAD;
  for (int j = 0; j < 5; ++j) {
    int col = j * 64 + lane;
    float v = (inr && col < DDIM) ? src[col] : 0.0f;
    dst[col] = f2bf(v);
  }
}

// ---- K2: conv weight transform -> wT[k][o][i] bf16, o/i padded to 320 with 0
__global__ __launch_bounds__(256) void wt_kernel(
    const float* __restrict__ w, unsigned short* __restrict__ wT) {
  int k = blockIdx.x / DPAD, o = blockIdx.x % DPAD;
  for (int i = threadIdx.x; i < DPAD; i += 256) {
    float v = (o < DDIM && i < DDIM) ? w[((size_t)o * DDIM + i) * KSZ + k] : 0.0f;
    wT[((size_t)k * DPAD + o) * DPAD + i] = f2bf(v);
  }
}

// ---- K3: U transform -> Ub[l][d] bf16, l padded to 8928, d to 320 with 0
__global__ __launch_bounds__(256) void ut_kernel(
    const float* __restrict__ U, unsigned short* __restrict__ Ub) {
  int l = blockIdx.x;
  for (int d = threadIdx.x; d < DPAD; d += 256) {
    float v = (l < LDIM && d < DDIM) ? U[(size_t)l * DDIM + d] : 0.0f;
    Ub[(size_t)l * DPAD + d] = f2bf(v);
  }
}

// ---- K4: conv via MFMA. h[b][t][o] bf16 (t-major for attn B-frags), relu+bias
// CTN 64->32: grid 264->520 blocks (~2 blocks/CU instead of 1) — conv was
// latency-bound at 1 wave/SIMD. acc[5][2], LDS 26.9KB, launch_bounds(256,3).
#define CTN 32
#define CROWS 41          // CTN + KSZ - 1
#define CSTRIDE 328       // 656B/row -> 2-way max conflicts
__global__ __launch_bounds__(256, 3) void conv_mfma_kernel(
    const unsigned short* __restrict__ xp, const unsigned short* __restrict__ wT,
    const float* __restrict__ bias, unsigned short* __restrict__ h) {
  __shared__ unsigned short xls[CROWS * CSTRIDE];
  int b = blockIdx.x & 7, tb = blockIdx.x >> 3;
  int t0 = tb * CTN;
  int tid = threadIdx.x;
  {
    const unsigned short* src = xp + (size_t)b * TPADDED * DPAD;
    for (int idx = tid; idx < CROWS * (DPAD / 8); idx += 256) {
      int r = idx / 40, c8 = idx % 40;
      int tp = t0 + r;
      int4 v = make_int4(0, 0, 0, 0);
      if (tp < TPADDED) v = *(const int4*)&src[(size_t)tp * DPAD + c8 * 8];
      *(int4*)&xls[r * CSTRIDE + c8 * 8] = v;
    }
  }
  __syncthreads();
  int w = tid >> 6, lane = tid & 63;
  int l15 = lane & 15, quad = lane >> 4;
  f4v acc[5][2];
#pragma unroll
  for (int mf = 0; mf < 5; ++mf) {
    float bv[4];
#pragma unroll
    for (int r = 0; r < 4; ++r) {
      int o = w * 80 + mf * 16 + quad * 4 + r;
      bv[r] = (o < DDIM) ? bias[o] : 0.0f;
    }
#pragma unroll
    for (int nf = 0; nf < 2; ++nf) {
      acc[mf][nf][0] = bv[0]; acc[mf][nf][1] = bv[1];
      acc[mf][nf][2] = bv[2]; acc[mf][nf][3] = bv[3];
    }
  }
  s8v Acur[5], Anext[5];
#pragma unroll
  for (int mf = 0; mf < 5; ++mf)
    Acur[mf] = *(const s8v*)&wT[(size_t)(w * 80 + mf * 16 + l15) * DPAD + quad * 8];
  for (int iter = 0; iter < 100; ++iter) {
    int kc = iter / 10, it = iter % 10;
    if (iter < 99) {
      int kn = (iter + 1) / 10, itn = (iter + 1) % 10;
#pragma unroll
      for (int mf = 0; mf < 5; ++mf)
        Anext[mf] = *(const s8v*)&wT[((size_t)kn * DPAD + w * 80 + mf * 16 + l15) * DPAD + itn * 32 + quad * 8];
    }
    s8v Bv[2];
#pragma unroll
    for (int nf = 0; nf < 2; ++nf) {
      int rrow = nf * 16 + l15 + kc;
      Bv[nf] = *(const s8v*)&xls[rrow * CSTRIDE + it * 32 + quad * 8];
    }
#pragma unroll
    for (int mf = 0; mf < 5; ++mf)
#pragma unroll
      for (int nf = 0; nf < 2; ++nf)
        acc[mf][nf] = __builtin_amdgcn_mfma_f32_16x16x32_bf16(Acur[mf], Bv[nf], acc[mf][nf], 0, 0, 0);
#pragma unroll
    for (int mf = 0; mf < 5; ++mf) Acur[mf] = Anext[mf];
  }
#pragma unroll
  for (int mf = 0; mf < 5; ++mf) {
    int obase = w * 80 + mf * 16 + quad * 4;
#pragma unroll
    for (int nf = 0; nf < 2; ++nf) {
      int t = t0 + nf * 16 + l15;
      if (t < TPRIME) {
        unsigned short pk[4];
#pragma unroll
        for (int r = 0; r < 4; ++r) pk[r] = f2bf(fmaxf(acc[mf][nf][r], 0.0f));
        *(uint2*)&h[((size_t)b * TALLOC + t) * DPAD + obase] = *(uint2*)pk;
      }
    }
  }
}

// ---- K5: scores (U . h) via MFMA + fused softmax-weighted mean
// RESTRUCTURED: waves split L (32 l each), not t. U fragments are t-invariant,
// so each wave holds all 20 A-frags in 80 VGPRs (loaded once) — kills the
// 3M redundant LDS A-reads and the cross-wave LDS reduction entirely.
// h streamed through double-buffered LDS (32-t tiles), reg-staged 2-deep
// pipeline with raw s_barrier + lgkmcnt(0) only (global loads stay in flight
// across the barrier). LDS 41KB + ~165 VGPR -> 3 blocks/CU.
__global__ __launch_bounds__(256, 3) void attn_mfma_kernel(
    const unsigned short* __restrict__ h, const unsigned short* __restrict__ Ub,
    const float* __restrict__ fcb, float* __restrict__ out) {
  __shared__ unsigned short hls[2][TSTG * HSTR];   // 2 x 20992B = 41984B
  int b = blockIdx.x & 7, lb = blockIdx.x >> 3;
  int tid = threadIdx.x;
  int w = tid >> 6, lane = tid & 63;
  int l15 = lane & 15, quad = lane >> 4;
  const unsigned short* hb = h + (size_t)b * TALLOC * DPAD;

  // A fragments (U) in registers for the whole kernel: wave covers 32 l-rows
  s8v A[2][10];
  {
    int lr0 = lb * 128 + w * 32 + l15;
#pragma unroll
    for (int mf = 0; mf < 2; ++mf) {
      int lr = lr0 + mf * 16;
      if (lr >= LPAD) lr = LPAD - 1;          // clamped rows masked at store
      const unsigned short* up = Ub + (size_t)lr * DPAD + quad * 8;
#pragma unroll
      for (int kc = 0; kc < 10; ++kc)
        A[mf][kc] = *(const s8v*)&up[kc * 32];
    }
  }

  // staging map: thread handles int4 chunk idx = tid + j*256 -> (row, col8)
  int sr[5], sc[5];
#pragma unroll
  for (int j = 0; j < 5; ++j) { int idx = tid + j * 256; sr[j] = idx / 40; sc[j] = idx % 40; }

  int4 g[5];
  // prologue: tile 0 -> buf0, then issue tile-1 loads (left in flight)
#pragma unroll
  for (int j = 0; j < 5; ++j)
    g[j] = *(const int4*)&hb[(size_t)sr[j] * DPAD + sc[j] * 8];
#pragma unroll
  for (int j = 0; j < 5; ++j)
    *(int4*)&hls[0][sr[j] * HSTR + sc[j] * 8] = g[j];
#pragma unroll
  for (int j = 0; j < 5; ++j)
    g[j] = *(const int4*)&hb[(size_t)(TSTG + sr[j]) * DPAD + sc[j] * 8];
  asm volatile("s_waitcnt lgkmcnt(0)" ::: "memory");
  __builtin_amdgcn_s_barrier();

  float se[2][4], sw[2][4];
#pragma unroll
  for (int mf = 0; mf < 2; ++mf)
#pragma unroll
    for (int r = 0; r < 4; ++r) { se[mf][r] = 0.0f; sw[mf][r] = 0.0f; }

  int cur = 0;
  for (int t = 0; t < NTT; ++t) {
    int t0 = t * TSTG;
    const unsigned short* bufc = &hls[cur][0];
    f4v acc[2][2];
#pragma unroll
    for (int mf = 0; mf < 2; ++mf)
#pragma unroll
      for (int nf = 0; nf < 2; ++nf) {
        acc[mf][nf][0] = 0.0f; acc[mf][nf][1] = 0.0f;
        acc[mf][nf][2] = 0.0f; acc[mf][nf][3] = 0.0f;
      }
#pragma unroll
    for (int kc = 0; kc < 10; ++kc) {
      s8v Bv[2];
#pragma unroll
      for (int nf = 0; nf < 2; ++nf)
        Bv[nf] = *(const s8v*)&bufc[(nf * 16 + l15) * HSTR + kc * 32 + quad * 8];
#pragma unroll
      for (int mf = 0; mf < 2; ++mf)
#pragma unroll
        for (int nf = 0; nf < 2; ++nf)
          acc[mf][nf] = __builtin_amdgcn_mfma_f32_16x16x32_bf16(A[mf][kc], Bv[nf], acc[mf][nf], 0, 0, 0);
    }
    // fused softmax-weighted accumulation (per lane: one t-col, 8 l-rows)
#pragma unroll
    for (int nf = 0; nf < 2; ++nf) {
      bool valid = (t0 + nf * 16 + l15) < TPRIME;
#pragma unroll
      for (int mf = 0; mf < 2; ++mf)
#pragma unroll
        for (int r = 0; r < 4; ++r) {
          float s = acc[mf][nf][r];
          float e = valid ? __expf(s) : 0.0f;
          se[mf][r] += e;
          sw[mf][r] = fmaf(e, s, sw[mf][r]);
        }
    }
    if (t + 1 < NTT) {
      // write tile t+1 (loads issued one full tile ago — latency covered)
      unsigned short* bufn = &hls[cur ^ 1][0];
#pragma unroll
      for (int j = 0; j < 5; ++j)
        *(int4*)&bufn[sr[j] * HSTR + sc[j] * 8] = g[j];
      if (t + 2 < NTT) {
        int tb2 = (t + 2) * TSTG;
#pragma unroll
        for (int j = 0; j < 5; ++j)
          g[j] = *(const int4*)&hb[(size_t)(tb2 + sr[j]) * DPAD + sc[j] * 8];
      }
      // raw barrier: drain LDS writes only; keep global loads in flight
      asm volatile("s_waitcnt lgkmcnt(0)" ::: "memory");
      __builtin_amdgcn_s_barrier();
      cur ^= 1;
    }
  }

  // reduce over the 16 t-columns (l15 lanes) — no cross-wave reduction needed
#pragma unroll
  for (int mf = 0; mf < 2; ++mf)
#pragma unroll
    for (int r = 0; r < 4; ++r) {
      float a = se[mf][r], c = sw[mf][r];
#pragma unroll
      for (int off = 1; off < 16; off <<= 1) {
        a += __shfl_xor(a, off, 64);
        c += __shfl_xor(c, off, 64);
      }
      if (l15 == 0) {
        int l = lb * 128 + w * 32 + mf * 16 + quad * 4 + r;
        if (l < LDIM) out[(size_t)b * LDIM + l] = c / a + fcb[l];
      }
    }
}

extern "C" void kernel_launch(void* const* d_in, const int* in_sizes, int n_in,
                              void* d_out, int out_size, void* d_ws, size_t ws_size,
                              hipStream_t stream) {
  const int*   ids     = (const int*)d_in[0];
  const float* embed_w = (const float*)d_in[1];
  const float* conv_w  = (const float*)d_in[2];
  const float* conv_b  = (const float*)d_in[3];
  const float* U       = (const float*)d_in[4];
  const float* fc_bias = (const float*)d_in[5];
  float* out = (float*)d_out;

  unsigned char* p = (unsigned char*)d_ws;
  unsigned short* xp = (unsigned short*)p;                 p += (size_t)BATCH * TPADDED * DPAD * 2;
  unsigned short* hb = (unsigned short*)p;                 p += (size_t)BATCH * TALLOC * DPAD * 2;
  unsigned short* wT = (unsigned short*)p;                 p += (size_t)KSZ * DPAD * DPAD * 2;
  unsigned short* Ub = (unsigned short*)p;

  hipLaunchKernelGGL(gather_kernel, dim3(BATCH * TPADDED / 4), dim3(256), 0, stream,
                     ids, embed_w, xp);
  hipLaunchKernelGGL(wt_kernel, dim3(KSZ * DPAD), dim3(256), 0, stream, conv_w, wT);
  hipLaunchKernelGGL(ut_kernel, dim3(LPAD), dim3(256), 0, stream, U, Ub);
  hipLaunchKernelGGL(conv_mfma_kernel, dim3(BATCH * NTT), dim3(256), 0, stream,
                     xp, wT, conv_b, hb);
  hipLaunchKernelGGL(attn_mfma_kernel, dim3(BATCH * LBLK), dim3(256), 0, stream,
                     hb, Ub, fc_bias, out);
}

// Round 2
// 336.269 us; speedup vs baseline: 1.7179x; 1.7179x over previous
//
#include <hip/hip_runtime.h>

#define VOCAB   50000
#define LDIM    8921
#define DDIM    300
#define DPAD    320
#define KSZ     10
#define BATCH   8
#define TSEQ    2048
#define PADL    9
#define TPRIME  2057
#define TPADDED 2066
#define LPAD    8928

// ---- attn tiling
#define TSTG    32                 // t rows per LDS tile
#define NTT     65                 // ceil(TPRIME/TSTG)
#define TALLOC  (NTT * TSTG)       // 2080 h rows per batch (tail rows zeroed by conv)
#define LBLK    70                 // ceil(LDIM/128) l-blocks

typedef short s8v __attribute__((ext_vector_type(8)));   // 8 x bf16 bits
typedef float f4v __attribute__((ext_vector_type(4)));

typedef const __attribute__((address_space(1))) unsigned int* gas_ptr;
typedef __attribute__((address_space(3))) unsigned int* las_ptr;

__device__ inline unsigned short f2bf(float f) {
  union { float f; unsigned u; } v; v.f = f;
  unsigned r = v.u + 0x7FFF + ((v.u >> 16) & 1);
  return (unsigned short)(r >> 16);
}

// ---- K1: embedding gather -> xp_bf16[b][tau][DPAD], zero-padded rows/cols
__global__ __launch_bounds__(256) void gather_kernel(
    const int* __restrict__ ids, const float* __restrict__ embed_w,
    unsigned short* __restrict__ xp) {
  int wid = blockIdx.x * 4 + (threadIdx.x >> 6);
  int lane = threadIdx.x & 63;
  int b = wid / TPADDED, tau = wid % TPADDED;
  bool inr = (tau >= PADL) && (tau < PADL + TSEQ);
  int row = inr ? ids[b * TSEQ + (tau - PADL)] : 0;
  const float* src = embed_w + (size_t)row * DDIM;
  unsigned short* dst = xp + ((size_t)b * TPADDED + tau) * DPAD;
  for (int j = 0; j < 5; ++j) {
    int col = j * 64 + lane;
    float v = (inr && col < DDIM) ? src[col] : 0.0f;
    dst[col] = f2bf(v);
  }
}

// ---- K2: conv weight transform -> wT[k][o][i] bf16, o/i padded to 320 with 0
__global__ __launch_bounds__(256) void wt_kernel(
    const float* __restrict__ w, unsigned short* __restrict__ wT) {
  int k = blockIdx.x / DPAD, o = blockIdx.x % DPAD;
  for (int i = threadIdx.x; i < DPAD; i += 256) {
    float v = (o < DDIM && i < DDIM) ? w[((size_t)o * DDIM + i) * KSZ + k] : 0.0f;
    wT[((size_t)k * DPAD + o) * DPAD + i] = f2bf(v);
  }
}

// ---- K3: U transform -> Ub[l][d] bf16, l padded to 8928, d to 320 with 0
__global__ __launch_bounds__(256) void ut_kernel(
    const float* __restrict__ U, unsigned short* __restrict__ Ub) {
  int l = blockIdx.x;
  for (int d = threadIdx.x; d < DPAD; d += 256) {
    float v = (l < LDIM && d < DDIM) ? U[(size_t)l * DDIM + d] : 0.0f;
    Ub[(size_t)l * DPAD + d] = f2bf(v);
  }
}

// ---- K4: conv via MFMA (round-0 config: CTN=64, 2 blocks/CU).
// h[b][t][o] bf16, t-major; relu+bias; rows [TPRIME,TALLOC) written as ZEROS
// so attn can consume all TALLOC rows unmasked-garbage-free.
#define CTN 64
#define CROWS 73          // CTN + KSZ - 1
#define CSTRIDE 328       // 656B/row -> benign conflicts
__global__ __launch_bounds__(256, 2) void conv_mfma_kernel(
    const unsigned short* __restrict__ xp, const unsigned short* __restrict__ wT,
    const float* __restrict__ bias, unsigned short* __restrict__ h) {
  __shared__ unsigned short xls[CROWS * CSTRIDE];
  int b = blockIdx.x & 7, tb = blockIdx.x >> 3;
  int t0 = tb * CTN;
  int tid = threadIdx.x;
  {
    const unsigned short* src = xp + (size_t)b * TPADDED * DPAD;
    for (int idx = tid; idx < CROWS * (DPAD / 8); idx += 256) {
      int r = idx / 40, c8 = idx % 40;
      int tp = t0 + r;
      int4 v = make_int4(0, 0, 0, 0);
      if (tp < TPADDED) v = *(const int4*)&src[(size_t)tp * DPAD + c8 * 8];
      *(int4*)&xls[r * CSTRIDE + c8 * 8] = v;
    }
  }
  __syncthreads();
  int w = tid >> 6, lane = tid & 63;
  int l15 = lane & 15, quad = lane >> 4;
  f4v acc[5][4];
#pragma unroll
  for (int mf = 0; mf < 5; ++mf) {
    float bv[4];
#pragma unroll
    for (int r = 0; r < 4; ++r) {
      int o = w * 80 + mf * 16 + quad * 4 + r;
      bv[r] = (o < DDIM) ? bias[o] : 0.0f;
    }
#pragma unroll
    for (int nf = 0; nf < 4; ++nf) {
      acc[mf][nf][0] = bv[0]; acc[mf][nf][1] = bv[1];
      acc[mf][nf][2] = bv[2]; acc[mf][nf][3] = bv[3];
    }
  }
  s8v Acur[5], Anext[5];
#pragma unroll
  for (int mf = 0; mf < 5; ++mf)
    Acur[mf] = *(const s8v*)&wT[(size_t)(w * 80 + mf * 16 + l15) * DPAD + quad * 8];
  for (int iter = 0; iter < 100; ++iter) {
    int kc = iter / 10, it = iter % 10;
    if (iter < 99) {
      int kn = (iter + 1) / 10, itn = (iter + 1) % 10;
#pragma unroll
      for (int mf = 0; mf < 5; ++mf)
        Anext[mf] = *(const s8v*)&wT[((size_t)kn * DPAD + w * 80 + mf * 16 + l15) * DPAD + itn * 32 + quad * 8];
    }
    s8v Bv[4];
#pragma unroll
    for (int nf = 0; nf < 4; ++nf) {
      int rrow = nf * 16 + l15 + kc;
      Bv[nf] = *(const s8v*)&xls[rrow * CSTRIDE + it * 32 + quad * 8];
    }
#pragma unroll
    for (int mf = 0; mf < 5; ++mf)
#pragma unroll
      for (int nf = 0; nf < 4; ++nf)
        acc[mf][nf] = __builtin_amdgcn_mfma_f32_16x16x32_bf16(Acur[mf], Bv[nf], acc[mf][nf], 0, 0, 0);
#pragma unroll
    for (int mf = 0; mf < 5; ++mf) Acur[mf] = Anext[mf];
  }
#pragma unroll
  for (int mf = 0; mf < 5; ++mf) {
    int obase = w * 80 + mf * 16 + quad * 4;
#pragma unroll
    for (int nf = 0; nf < 4; ++nf) {
      int t = t0 + nf * 16 + l15;
      if (t < TALLOC) {
        bool live = t < TPRIME;
        unsigned short pk[4];
#pragma unroll
        for (int r = 0; r < 4; ++r)
          pk[r] = live ? f2bf(fmaxf(acc[mf][nf][r], 0.0f)) : (unsigned short)0;
        *(uint2*)&h[((size_t)b * TALLOC + t) * DPAD + obase] = *(uint2*)pk;
      }
    }
  }
}

// ---- K5: scores (U . h) via MFMA + fused softmax-weighted mean.
// Waves split L (32 l each); all 20 U A-frags live in 80 VGPRs, loaded once.
// h streamed via global_load_lds DMA (no staging VGPRs / ds_writes):
//   linear LDS dest + involution-swizzled SOURCE chunks (c ^= r&7 within
//   128B groups) + same XOR on read side (rule #21) -> conflict-free reads
//   with pad-free 640B rows (LDS 40960B -> 3 blocks/CU).
// Depth-1 prefetch; raw s_barrier + vmcnt(0) drained a full tile after issue.
__global__ __launch_bounds__(256, 3) void attn_mfma_kernel(
    const unsigned short* __restrict__ h, const unsigned short* __restrict__ Ub,
    const float* __restrict__ fcb, float* __restrict__ out) {
  __shared__ unsigned short hls[2 * TSTG * DPAD];   // 2 x 10240 elems = 40960B
  int b = blockIdx.x & 7, lb = blockIdx.x >> 3;
  int tid = threadIdx.x;
  int w = tid >> 6, lane = tid & 63;
  int l15 = lane & 15, quad = lane >> 4;
  const unsigned short* hb = h + (size_t)b * TALLOC * DPAD;

  // A fragments (U) in registers for the whole kernel: wave covers 32 l-rows
  s8v A[2][10];
  {
    int lr0 = lb * 128 + w * 32 + l15;
#pragma unroll
    for (int mf = 0; mf < 2; ++mf) {
      int lr = lr0 + mf * 16;
      if (lr >= LPAD) lr = LPAD - 1;          // clamped rows masked at store
      const unsigned short* up = Ub + (size_t)lr * DPAD + quad * 8;
#pragma unroll
      for (int kc = 0; kc < 10; ++kc)
        A[mf][kc] = *(const s8v*)&up[kc * 32];
    }
  }

  // DMA staging map: wave w fills LDS elems [w*2560, w*2560+2560) in 5 x 1KB.
  // lane's LDS chunk g = w*320 + j*64 + lane -> row r = g/40, chunk c = g%40;
  // global source chunk = c ^ (r&7)  (involution, stays in 128B group)
  int srcoff[5];
#pragma unroll
  for (int j = 0; j < 5; ++j) {
    int g = w * 320 + j * 64 + lane;
    int r = g / 40, c = g % 40;
    srcoff[j] = r * DPAD + ((c ^ (r & 7)) * 8);
  }

  // prologue: DMA tile 0 -> buf0
#pragma unroll
  for (int j = 0; j < 5; ++j)
    __builtin_amdgcn_global_load_lds((gas_ptr)(const void*)(hb + srcoff[j]),
                                     (las_ptr)(void*)&hls[w * 2560 + j * 512],
                                     16, 0, 0);
  asm volatile("s_waitcnt vmcnt(0)" ::: "memory");
  __builtin_amdgcn_s_barrier();

  float se[2][4], sw[2][4];
#pragma unroll
  for (int mf = 0; mf < 2; ++mf)
#pragma unroll
    for (int r = 0; r < 4; ++r) { se[mf][r] = 0.0f; sw[mf][r] = 0.0f; }

  int xr8 = (l15 & 7) * 8;            // read-side XOR (elem units)
  int rowb0 = l15 * DPAD;             // nf=0 row base
  int rowb1 = (16 + l15) * DPAD;      // nf=1 row base
  int bufsel = 0;
  for (int t = 0; t < NTT; ++t) {
    // issue DMA for tile t+1 into the other buffer (latency hidden by compute)
    if (t + 1 < NTT) {
      const unsigned short* src = hb + (size_t)(t + 1) * TSTG * DPAD;
      int dstb = (bufsel ^ 1) * 10240 + w * 2560;
#pragma unroll
      for (int j = 0; j < 5; ++j)
        __builtin_amdgcn_global_load_lds((gas_ptr)(const void*)(src + srcoff[j]),
                                         (las_ptr)(void*)&hls[dstb + j * 512],
                                         16, 0, 0);
    }
    const unsigned short* bufc = &hls[bufsel * 10240];
    f4v acc[2][2];
#pragma unroll
    for (int mf = 0; mf < 2; ++mf)
#pragma unroll
      for (int nf = 0; nf < 2; ++nf) {
        acc[mf][nf][0] = 0.0f; acc[mf][nf][1] = 0.0f;
        acc[mf][nf][2] = 0.0f; acc[mf][nf][3] = 0.0f;
      }
#pragma unroll
    for (int kc = 0; kc < 10; ++kc) {
      int ko = (kc * 32 + quad * 8) ^ xr8;
      s8v Bv0 = *(const s8v*)&bufc[rowb0 + ko];
      s8v Bv1 = *(const s8v*)&bufc[rowb1 + ko];
      acc[0][0] = __builtin_amdgcn_mfma_f32_16x16x32_bf16(A[0][kc], Bv0, acc[0][0], 0, 0, 0);
      acc[0][1] = __builtin_amdgcn_mfma_f32_16x16x32_bf16(A[0][kc], Bv1, acc[0][1], 0, 0, 0);
      acc[1][0] = __builtin_amdgcn_mfma_f32_16x16x32_bf16(A[1][kc], Bv0, acc[1][0], 0, 0, 0);
      acc[1][1] = __builtin_amdgcn_mfma_f32_16x16x32_bf16(A[1][kc], Bv1, acc[1][1], 0, 0, 0);
    }
    // fused softmax-weighted accumulation (tail rows of h are zeros, t>=TPRIME masked)
    int tb0 = t * TSTG;
#pragma unroll
    for (int nf = 0; nf < 2; ++nf) {
      bool valid = (tb0 + nf * 16 + l15) < TPRIME;
#pragma unroll
      for (int mf = 0; mf < 2; ++mf)
#pragma unroll
        for (int r = 0; r < 4; ++r) {
          float s = acc[mf][nf][r];
          float e = valid ? __expf(s) : 0.0f;
          se[mf][r] += e;
          sw[mf][r] = fmaf(e, valid ? s : 0.0f, sw[mf][r]);
        }
    }
    // drain this iter's DMA (issued ~a full tile of compute ago), sync, swap
    asm volatile("s_waitcnt vmcnt(0)" ::: "memory");
    __builtin_amdgcn_s_barrier();
    bufsel ^= 1;
  }

  // reduce over the 16 t-columns (l15 lanes) — no cross-wave reduction needed
#pragma unroll
  for (int mf = 0; mf < 2; ++mf)
#pragma unroll
    for (int r = 0; r < 4; ++r) {
      float a = se[mf][r], c = sw[mf][r];
#pragma unroll
      for (int off = 1; off < 16; off <<= 1) {
        a += __shfl_xor(a, off, 64);
        c += __shfl_xor(c, off, 64);
      }
      if (l15 == 0) {
        int l = lb * 128 + w * 32 + mf * 16 + quad * 4 + r;
        if (l < LDIM) out[(size_t)b * LDIM + l] = c / a + fcb[l];
      }
    }
}

extern "C" void kernel_launch(void* const* d_in, const int* in_sizes, int n_in,
                              void* d_out, int out_size, void* d_ws, size_t ws_size,
                              hipStream_t stream) {
  const int*   ids     = (const int*)d_in[0];
  const float* embed_w = (const float*)d_in[1];
  const float* conv_w  = (const float*)d_in[2];
  const float* conv_b  = (const float*)d_in[3];
  const float* U       = (const float*)d_in[4];
  const float* fc_bias = (const float*)d_in[5];
  float* out = (float*)d_out;

  unsigned char* p = (unsigned char*)d_ws;
  unsigned short* xp = (unsigned short*)p;                 p += (size_t)BATCH * TPADDED * DPAD * 2;
  unsigned short* hb = (unsigned short*)p;                 p += (size_t)BATCH * TALLOC * DPAD * 2;
  unsigned short* wT = (unsigned short*)p;                 p += (size_t)KSZ * DPAD * DPAD * 2;
  unsigned short* Ub = (unsigned short*)p;

  hipLaunchKernelGGL(gather_kernel, dim3(BATCH * TPADDED / 4), dim3(256), 0, stream,
                     ids, embed_w, xp);
  hipLaunchKernelGGL(wt_kernel, dim3(KSZ * DPAD), dim3(256), 0, stream, conv_w, wT);
  hipLaunchKernelGGL(ut_kernel, dim3(LPAD), dim3(256), 0, stream, U, Ub);
  hipLaunchKernelGGL(conv_mfma_kernel, dim3(BATCH * 33), dim3(256), 0, stream,
                     xp, wT, conv_b, hb);
  hipLaunchKernelGGL(attn_mfma_kernel, dim3(BATCH * LBLK), dim3(256), 0, stream,
                     hb, Ub, fc_bias, out);
}